// Round 10
// baseline (2689.557 us; speedup 1.0000x reference)
//
#include <hip/hip_runtime.h>
#include <math.h>

typedef __bf16 bf16x8 __attribute__((ext_vector_type(8)));
typedef float f32x4 __attribute__((ext_vector_type(4)));
typedef unsigned uint4v __attribute__((ext_vector_type(4)));
typedef unsigned long long u64;

#define HD 512
#define NB 128
#define NI 32
#define NL 96
#define NS 16
#define NF 24
#define NSTEP 23
#define TS2 72

#define MFMA16(a,b,c) __builtin_amdgcn_mfma_f32_16x16x32_bf16(a,b,c,0,0,0)

union FragU { uint4v u; bf16x8 b; };

__device__ __forceinline__ unsigned short f2bf(float f) {
    union { float f; unsigned u; } v; v.f = f;
    unsigned r = v.u + 0x7fffu + ((v.u >> 16) & 1u);
    return (unsigned short)(r >> 16);
}
__device__ __forceinline__ float bf2f(unsigned short h) {
    union { unsigned u; float f; } v; v.u = ((unsigned)h) << 16;
    return v.f;
}
__device__ __forceinline__ void split_bf(float v, unsigned short& hi, unsigned short& lo) {
    unsigned short h = f2bf(v);
    hi = h;
    lo = f2bf(v - bf2f(h));
}
__device__ __forceinline__ float sigm(float x) { return 1.0f / (1.0f + __expf(-x)); }
__device__ __forceinline__ float softp(float x) {
    return fmaxf(x, 0.0f) + log1pf(__expf(-fabsf(x)));
}
__device__ __forceinline__ bf16x8 ld8(const unsigned short* p) {
    return *reinterpret_cast<const bf16x8*>(p);
}
__device__ __forceinline__ f32x4 mfma3(bf16x8 ahi, bf16x8 alo, const unsigned short* bp, f32x4 c) {
    bf16x8 bhi = ld8(bp);
    bf16x8 blo = ld8(bp + 8);
    c = MFMA16(ahi, bhi, c);
    c = MFMA16(alo, bhi, c);
    c = MFMA16(ahi, blo, c);
    return c;
}

// ======== exchange tile layout: 2 KB/tile = hi-plane [lane*16] (1 KB) + lo-plane (+1024) ========
// ---- agent path (memory-side coherent; works across XCDs) ----
__device__ __forceinline__ void st_frag_agent(u64* tile, int lane, bf16x8 hi, bf16x8 lo) {
    union { bf16x8 v; u64 q[2]; } h, l;
    h.v = hi; l.v = lo;
    u64* t = tile + lane * 2;
    __hip_atomic_store(t + 0,   h.q[0], __ATOMIC_RELAXED, __HIP_MEMORY_SCOPE_AGENT);
    __hip_atomic_store(t + 1,   h.q[1], __ATOMIC_RELAXED, __HIP_MEMORY_SCOPE_AGENT);
    __hip_atomic_store(t + 128, l.q[0], __ATOMIC_RELAXED, __HIP_MEMORY_SCOPE_AGENT);
    __hip_atomic_store(t + 129, l.q[1], __ATOMIC_RELAXED, __HIP_MEMORY_SCOPE_AGENT);
}
__device__ __forceinline__ void ld_frag_agent(const u64* tile, int lane, bf16x8& hi, bf16x8& lo) {
    union { bf16x8 v; u64 q[2]; } h, l;
    const u64* t = tile + lane * 2;
    h.q[0] = __hip_atomic_load(t + 0,   __ATOMIC_RELAXED, __HIP_MEMORY_SCOPE_AGENT);
    h.q[1] = __hip_atomic_load(t + 1,   __ATOMIC_RELAXED, __HIP_MEMORY_SCOPE_AGENT);
    l.q[0] = __hip_atomic_load(t + 128, __ATOMIC_RELAXED, __HIP_MEMORY_SCOPE_AGENT);
    l.q[1] = __hip_atomic_load(t + 129, __ATOMIC_RELAXED, __HIP_MEMORY_SCOPE_AGENT);
    hi = h.v; lo = l.v;
}
// ---- fast path (XCD-local: sc0 stores write through to L2; sc0 loads bypass L1, hit L2).
//      ONLY valid when all group members share one XCD (runtime-verified).
//      NOTE gfx950 asm modifier order: `off offset:N sc0` (offset BEFORE cache flags). ----
__device__ __forceinline__ void st_frag_fast(u64* tile, int lane, bf16x8 hi, bf16x8 lo) {
    FragU h, l; h.b = hi; l.b = lo;
    char* p = (char*)tile + lane * 16;
    asm volatile("global_store_dwordx4 %0, %1, off sc0" :: "v"(p), "v"(h.u) : "memory");
    asm volatile("global_store_dwordx4 %0, %1, off offset:1024 sc0" :: "v"(p), "v"(l.u) : "memory");
}
__device__ __forceinline__ void ld2_fast(const char* pa,
    bf16x8& h0, bf16x8& l0, bf16x8& h1, bf16x8& l1) {
    FragU a0, b0, a1, b1;
    asm volatile(
        "global_load_dwordx4 %0, %4, off sc0\n\t"
        "global_load_dwordx4 %1, %4, off offset:1024 sc0\n\t"
        "global_load_dwordx4 %2, %4, off offset:2048 sc0\n\t"
        "global_load_dwordx4 %3, %4, off offset:3072 sc0\n\t"
        "s_waitcnt vmcnt(0)"
        : "=&v"(a0.u), "=&v"(b0.u), "=&v"(a1.u), "=&v"(b1.u)
        : "v"(pa) : "memory");
    h0 = a0.b; l0 = b0.b; h1 = a1.b; l1 = b1.b;
}
__device__ __forceinline__ void ld4_fast(const char* pa, const char* pb,
    bf16x8& h0, bf16x8& l0, bf16x8& h1, bf16x8& l1,
    bf16x8& h2, bf16x8& l2, bf16x8& h3, bf16x8& l3) {
    FragU a0, b0, a1, b1, a2, b2, a3, b3;
    asm volatile(
        "global_load_dwordx4 %0, %8, off sc0\n\t"
        "global_load_dwordx4 %1, %8, off offset:1024 sc0\n\t"
        "global_load_dwordx4 %2, %8, off offset:2048 sc0\n\t"
        "global_load_dwordx4 %3, %8, off offset:3072 sc0\n\t"
        "global_load_dwordx4 %4, %9, off sc0\n\t"
        "global_load_dwordx4 %5, %9, off offset:1024 sc0\n\t"
        "global_load_dwordx4 %6, %9, off offset:2048 sc0\n\t"
        "global_load_dwordx4 %7, %9, off offset:3072 sc0\n\t"
        "s_waitcnt vmcnt(0)"
        : "=&v"(a0.u), "=&v"(b0.u), "=&v"(a1.u), "=&v"(b1.u),
          "=&v"(a2.u), "=&v"(b2.u), "=&v"(a3.u), "=&v"(b3.u)
        : "v"(pa), "v"(pb) : "memory");
    h0 = a0.b; l0 = b0.b; h1 = a1.b; l1 = b1.b;
    h2 = a2.b; l2 = b2.b; h3 = a3.b; l3 = b3.b;
}
__device__ __forceinline__ void st_frag(u64* tile, int lane, bf16x8 hi, bf16x8 lo, bool fast) {
    if (fast) st_frag_fast(tile, lane, hi, lo);
    else      st_frag_agent(tile, lane, hi, lo);
}

// barrier: drain own vmem, block-barrier, memory-side relaxed counter, spin.
__device__ __forceinline__ void gbar(unsigned* ctr, unsigned target) {
    __builtin_amdgcn_s_waitcnt(0);
    __syncthreads();
    if (threadIdx.x == 0) {
        __hip_atomic_fetch_add(ctr, 1u, __ATOMIC_RELAXED, __HIP_MEMORY_SCOPE_AGENT);
        while (__hip_atomic_load(ctr, __ATOMIC_RELAXED, __HIP_MEMORY_SCOPE_AGENT) < target)
            __builtin_amdgcn_s_sleep(2);
    }
    __syncthreads();
}

// ---------- prep kernels ----------
__global__ void pack_w(const float* __restrict__ W, unsigned short* __restrict__ Wp,
                       int N, int K) {
    int idx = blockIdx.x * 256 + threadIdx.x;
    int total = (N / 16) * (K / 32) * 64;
    if (idx >= total) return;
    int lane = idx & 63;
    int t2 = idx >> 6;
    int KT = K / 32;
    int kt = t2 % KT, nt = t2 / KT;
    const float* src = W + (size_t)(nt * 16 + (lane & 15)) * K + kt * 32 + (lane >> 4) * 8;
    unsigned short* dst = Wp + (size_t)idx * 16;
    #pragma unroll
    for (int j = 0; j < 8; ++j) split_bf(src[j], dst[j], dst[8 + j]);
}
__global__ void pack_x(const float* __restrict__ x, unsigned short* __restrict__ xhi,
                       unsigned short* __restrict__ xlo) {
    int idx = blockIdx.x * 256 + threadIdx.x;
    if (idx >= NL * NB) return;
    int b = idx % NB, l = idx / NB;
    size_t base = (size_t)(l * NB + b) * NI;
    #pragma unroll
    for (int i = 0; i < NI; ++i)
        split_bf(x[((size_t)b * NI + i) * NL + l], xhi[base + i], xlo[base + i]);
}

// =================== fused cooperative kernel ===================
__global__ __launch_bounds__(512) void coop_all(
    const unsigned short* __restrict__ xhi, const unsigned short* __restrict__ xlo,
    const unsigned short* __restrict__ wih_p, const unsigned short* __restrict__ whh_p,
    const unsigned short* __restrict__ w1_p, const unsigned short* __restrict__ w2_p,
    const unsigned short* __restrict__ gw_p, const unsigned short* __restrict__ dwhh_p,
    const unsigned short* __restrict__ outw_p,
    const float* __restrict__ ebih, const float* __restrict__ ebhh,
    const float* __restrict__ fb1, const float* __restrict__ fb2,
    const float* __restrict__ gb, const float* __restrict__ dbih,
    const float* __restrict__ dbhh, const float* __restrict__ outb,
    const float* __restrict__ noise,
    u64* hE0, u64* hE1, u64* hEF, u64* hP0, u64* hP1, u64* uP,
    unsigned* h_encF, unsigned* xcdArr, float* out, unsigned* bar)
{
    const int bid = blockIdx.x;
    const int tid = threadIdx.x, lane = tid & 63, wv = tid >> 6;
    const int l15 = lane & 15, g4 = lane >> 4;
    const f32x4 zz = {0.f, 0.f, 0.f, 0.f};

    __shared__ float pred[4][8][16][16];
    __shared__ __align__(16) unsigned short Thi[64][TS2];
    __shared__ __align__(16) unsigned short Tlo[64][TS2];
    __shared__ unsigned sflags;

    // =============== prologue: publish XCD id, verify group uniformity ===============
    int xcc;
    asm volatile("s_getreg_b32 %0, hwreg(HW_REG_XCC_ID)" : "=s"(xcc));
    if (tid == 0) {
        sflags = 0;
        __hip_atomic_store(xcdArr + bid, (unsigned)xcc, __ATOMIC_RELAXED, __HIP_MEMORY_SCOPE_AGENT);
    }
    gbar(bar + 0 * 32, 256u);
    if (tid < 32) {   // encoder group: bids {bid&7 + 8k}
        unsigned v = __hip_atomic_load(xcdArr + ((bid & 7) + 8 * tid),
                                       __ATOMIC_RELAXED, __HIP_MEMORY_SCOPE_AGENT);
        if (v != (unsigned)xcc) atomicOr(&sflags, 1u);
    }
    if (tid < 8) {    // SDE group: bids {bid&31 + 32m}
        unsigned v = __hip_atomic_load(xcdArr + ((bid & 31) + 32 * tid),
                                       __ATOMIC_RELAXED, __HIP_MEMORY_SCOPE_AGENT);
        if (v != (unsigned)xcc) atomicOr(&sflags, 2u);
    }
    __syncthreads();
    const bool encFast = !(sflags & 1u);
    const bool sdeFast = !(sflags & 2u);

    // =============== encoder: group g (16 rows), slice n (16 units) ===============
    {
        const int g = bid & 7, n = bid >> 3;
        unsigned* ctr = bar + (2 + g) * 32;
        float hcell = 0.f;
        float cr = 0.f, cz = 0.f, binx = 0.f, bhnn = 0.f;
        const int crow = tid >> 4, cunit = tid & 15;
        if (tid < 256) {
            int u = n * 16 + cunit;
            cr = ebih[u] + ebhh[u];
            cz = ebih[HD + u] + ebhh[HD + u];
            binx = ebih[2 * HD + u];
            bhnn = ebhh[2 * HD + u];
        }
        u64* hEbuf[2] = {hE0, hE1};
        #pragma unroll 1
        for (int l = 0; l < NL; ++l) {
            const u64* cur = hEbuf[l & 1];
            u64* nxt = hEbuf[(l & 1) ^ 1];
            f32x4 pr = zz, pz = zz, pnh = zz, pnx = zz;
            if (wv == 0) {
                size_t xb = (size_t)(l * NB + g * 16 + l15) * NI + g4 * 8;
                bf16x8 axh = ld8(xhi + xb), axl = ld8(xlo + xb);
                pr  = mfma3(axh, axl, wih_p + ((size_t)(0 * 32 + n) * 64 + lane) * 16, pr);
                pz  = mfma3(axh, axl, wih_p + ((size_t)(1 * 32 + n) * 64 + lane) * 16, pz);
                pnx = mfma3(axh, axl, wih_p + ((size_t)(2 * 32 + n) * 64 + lane) * 16, pnx);
            }
            if (l > 0) {   // l==0: h == 0, skip hh matmul (also avoids reading uninit hE0)
                auto bodyE = [&](int kt, bf16x8 ah, bf16x8 al) {
                    pr  = mfma3(ah, al, whh_p + ((size_t)((0 * 32 + n) * 16 + kt) * 64 + lane) * 16, pr);
                    pz  = mfma3(ah, al, whh_p + ((size_t)((1 * 32 + n) * 16 + kt) * 64 + lane) * 16, pz);
                    pnh = mfma3(ah, al, whh_p + ((size_t)((2 * 32 + n) * 16 + kt) * 64 + lane) * 16, pnh);
                };
                if (encFast) {
                    const char* base = (const char*)(cur + (size_t)(g * 16 + wv * 2) * 256) + lane * 16;
                    bf16x8 a0, b0, a1, b1;
                    ld2_fast(base, a0, b0, a1, b1);
                    bodyE(wv * 2, a0, b0);
                    bodyE(wv * 2 + 1, a1, b1);
                } else {
                    #pragma unroll
                    for (int kk = 0; kk < 2; ++kk) {
                        bf16x8 ah, al;
                        ld_frag_agent(cur + (size_t)(g * 16 + wv * 2 + kk) * 256, lane, ah, al);
                        bodyE(wv * 2 + kk, ah, al);
                    }
                }
            }
            #pragma unroll
            for (int v = 0; v < 4; ++v) {
                pred[0][wv][g4 * 4 + v][l15] = pr[v];
                pred[1][wv][g4 * 4 + v][l15] = pz[v];
                pred[2][wv][g4 * 4 + v][l15] = pnh[v];
                if (wv == 0) pred[3][0][g4 * 4 + v][l15] = pnx[v];
            }
            __syncthreads();
            if (tid < 256) {
                float ar = 0.f, az = 0.f, anh_ = 0.f;
                #pragma unroll
                for (int w = 0; w < 8; ++w) {
                    ar += pred[0][w][crow][cunit];
                    az += pred[1][w][crow][cunit];
                    anh_ += pred[2][w][crow][cunit];
                }
                float anx_ = pred[3][0][crow][cunit];
                float r = sigm(ar + cr);
                float z = sigm(az + cz);
                float nn = tanhf(anx_ + binx + r * (anh_ + bhnn));
                hcell = (1.f - z) * nn + z * hcell;
                unsigned short hi, lo;
                split_bf(hcell, hi, lo);
                Thi[crow][cunit] = hi;
                Tlo[crow][cunit] = lo;
                if (l == NL - 1)
                    __hip_atomic_store(h_encF + (size_t)(g * 16 + crow) * HD + n * 16 + cunit,
                                       __float_as_uint(hcell),
                                       __ATOMIC_RELAXED, __HIP_MEMORY_SCOPE_AGENT);
            }
            __syncthreads();
            if (tid < 32) {
                int half = n & 1, kt = n >> 1;
                int lp = half * 32 + tid;
                bf16x8 vh = *(const bf16x8*)&Thi[tid & 15][(tid >> 4) * 8];
                bf16x8 vl = *(const bf16x8*)&Tlo[tid & 15][(tid >> 4) * 8];
                if (l == NL - 1)   // final state: cross-XCD consumers -> agent-only buffer
                    st_frag_agent(hEF + (size_t)(g * 16 + kt) * 256, lp, vh, vl);
                else
                    st_frag(nxt + (size_t)(g * 16 + kt) * 256, lp, vh, vl, encFast);
            }
            gbar(ctr, 32u * (l + 1));
        }
    }

    // full-grid barrier: h_encF + hEF (agent) visible to all XCDs
    gbar(bar + 1 * 32, 256u);

    // ====== SDE + decoder: 32 groups x 8 blocks; group = 64 rows, slice = 64 units ======
    const int g2 = (bid & 7) * 4 + ((bid >> 3) & 3);
    const int n2 = bid >> 5;
    unsigned* ctr2 = bar + (10 + g2) * 32;
    const int mt = wv & 3, nh = wv >> 2;
    const int smp = g2 >> 1;
    const int b0 = (g2 & 1) * 64 + mt * 16;
    const float dt = (float)NF / (float)NSTEP;
    const float sqdt = sqrtf(dt);

    float hreg[2][4];
    #pragma unroll
    for (int nt = 0; nt < 2; ++nt)
        #pragma unroll
        for (int v = 0; v < 4; ++v)
            hreg[nt][v] = __uint_as_float(__hip_atomic_load(
                h_encF + (size_t)(b0 + g4 * 4 + v) * HD + n2 * 64 + nh * 32 + nt * 16 + l15,
                __ATOMIC_RELAXED, __HIP_MEMORY_SCOPE_AGENT));

    float b1v[2], b2v[2], gbv[2];
    #pragma unroll
    for (int nt = 0; nt < 2; ++nt) {
        int u = n2 * 64 + nh * 32 + nt * 16 + l15;
        b1v[nt] = fb1[u]; b2v[nt] = fb2[u]; gbv[nt] = gb[u];
    }

    u64* hPb[2] = {hP0, hP1};
    int cur = 0;
    const int tmt = (tid >> 6) & 3, ko = tid >> 8, ln = tid & 63;

    #pragma unroll 1
    for (int st = 0; st < NSTEP; ++st) {
        const u64* hsrc = hPb[cur];
        const int tb = g2 * 4 + mt;
        // ---- phase A: u = tanh(h W1^T + b1)  AND  g-pre = h gW^T ----
        f32x4 au[2] = {zz, zz}, ag[2] = {zz, zz};
        {
            auto bodyA = [&](int kt, bf16x8 ah, bf16x8 al) {
                #pragma unroll
                for (int nt = 0; nt < 2; ++nt) {
                    int nn = n2 * 4 + nh * 2 + nt;
                    au[nt] = mfma3(ah, al, w1_p + ((size_t)(nn * 16 + kt) * 64 + lane) * 16, au[nt]);
                    ag[nt] = mfma3(ah, al, gw_p + ((size_t)(nn * 16 + kt) * 64 + lane) * 16, ag[nt]);
                }
            };
            if (st == 0) {
                int tb0 = (g2 & 1) * 4 + mt;
                #pragma unroll 4
                for (int kt = 0; kt < 16; ++kt) {
                    bf16x8 ah, al;
                    ld_frag_agent(hEF + (size_t)(tb0 * 16 + kt) * 256, lane, ah, al);
                    bodyA(kt, ah, al);
                }
            } else if (sdeFast) {
                const char* base = (const char*)(hsrc + (size_t)(tb * 16) * 256) + lane * 16;
                #pragma unroll
                for (int kb = 0; kb < 4; ++kb) {
                    bf16x8 a0, c0, a1, c1, a2, c2, a3, c3;
                    ld4_fast(base + kb * 8192, base + kb * 8192 + 4096,
                             a0, c0, a1, c1, a2, c2, a3, c3);
                    bodyA(kb * 4 + 0, a0, c0);
                    bodyA(kb * 4 + 1, a1, c1);
                    bodyA(kb * 4 + 2, a2, c2);
                    bodyA(kb * 4 + 3, a3, c3);
                }
            } else {
                #pragma unroll 4
                for (int kt = 0; kt < 16; ++kt) {
                    bf16x8 ah, al;
                    ld_frag_agent(hsrc + (size_t)(tb * 16 + kt) * 256, lane, ah, al);
                    bodyA(kt, ah, al);
                }
            }
        }
        #pragma unroll
        for (int nt = 0; nt < 2; ++nt)
            #pragma unroll
            for (int v = 0; v < 4; ++v) {
                unsigned short hi, lo;
                split_bf(tanhf(au[nt][v] + b1v[nt]), hi, lo);
                Thi[mt * 16 + g4 * 4 + v][nh * 32 + nt * 16 + l15] = hi;
                Tlo[mt * 16 + g4 * 4 + v][nh * 32 + nt * 16 + l15] = lo;
            }
        __syncthreads();
        {
            bf16x8 vh = *(const bf16x8*)&Thi[tmt * 16 + (ln & 15)][ko * 32 + (ln >> 4) * 8];
            bf16x8 vl = *(const bf16x8*)&Tlo[tmt * 16 + (ln & 15)][ko * 32 + (ln >> 4) * 8];
            st_frag(uP + (size_t)((g2 * 4 + tmt) * 16 + n2 * 2 + ko) * 256, ln, vh, vl, sdeFast);
        }
        gbar(ctr2, 8u * (2 * st + 1));
        // ---- phase B: f = u W2^T + b2 ----
        f32x4 af[2] = {zz, zz};
        {
            auto bodyB = [&](int kt, bf16x8 uh, bf16x8 ul) {
                #pragma unroll
                for (int nt = 0; nt < 2; ++nt) {
                    int nn = n2 * 4 + nh * 2 + nt;
                    af[nt] = mfma3(uh, ul, w2_p + ((size_t)(nn * 16 + kt) * 64 + lane) * 16, af[nt]);
                }
            };
            if (sdeFast) {
                const char* base = (const char*)(uP + (size_t)((g2 * 4 + mt) * 16) * 256) + lane * 16;
                #pragma unroll
                for (int kb = 0; kb < 4; ++kb) {
                    bf16x8 a0, c0, a1, c1, a2, c2, a3, c3;
                    ld4_fast(base + kb * 8192, base + kb * 8192 + 4096,
                             a0, c0, a1, c1, a2, c2, a3, c3);
                    bodyB(kb * 4 + 0, a0, c0);
                    bodyB(kb * 4 + 1, a1, c1);
                    bodyB(kb * 4 + 2, a2, c2);
                    bodyB(kb * 4 + 3, a3, c3);
                }
            } else {
                #pragma unroll 4
                for (int kt = 0; kt < 16; ++kt) {
                    bf16x8 uh, ul;
                    ld_frag_agent(uP + (size_t)((g2 * 4 + mt) * 16 + kt) * 256, lane, uh, ul);
                    bodyB(kt, uh, ul);
                }
            }
        }
        #pragma unroll
        for (int nt = 0; nt < 2; ++nt)
            #pragma unroll
            for (int v = 0; v < 4; ++v) {
                int b = b0 + g4 * 4 + v;
                size_t nidx = ((size_t)(smp * NSTEP + st) * NB + b) * HD
                              + n2 * 64 + nh * 32 + nt * 16 + l15;
                float nz = noise[nidx];
                float f = af[nt][v] + b2v[nt];
                float gg = softp(ag[nt][v] + gbv[nt]);
                hreg[nt][v] += f * dt + gg * sqdt * nz;
                unsigned short hi, lo;
                split_bf(hreg[nt][v], hi, lo);
                Thi[mt * 16 + g4 * 4 + v][nh * 32 + nt * 16 + l15] = hi;
                Tlo[mt * 16 + g4 * 4 + v][nh * 32 + nt * 16 + l15] = lo;
            }
        __syncthreads();
        {
            bf16x8 vh = *(const bf16x8*)&Thi[tmt * 16 + (ln & 15)][ko * 32 + (ln >> 4) * 8];
            bf16x8 vl = *(const bf16x8*)&Tlo[tmt * 16 + (ln & 15)][ko * 32 + (ln >> 4) * 8];
            st_frag(hPb[cur ^ 1] + (size_t)((g2 * 4 + tmt) * 16 + n2 * 2 + ko) * 256, ln, vh, vl, sdeFast);
        }
        cur ^= 1;
        gbar(ctr2, 8u * (2 * st + 2));
    }

    // =============== decoder GRU + out-proj ===============
    float crv[2], czv[2], binv[2], bhnv[2], obias[2];
    #pragma unroll
    for (int nt = 0; nt < 2; ++nt) {
        int u = n2 * 64 + nh * 32 + nt * 16 + l15;
        crv[nt] = dbih[u] + dbhh[u];
        czv[nt] = dbih[HD + u] + dbhh[HD + u];
        binv[nt] = dbih[2 * HD + u];
        bhnv[nt] = dbhh[2 * HD + u];
        obias[nt] = (n2 == 0 && nh == 0) ? outb[nt * 16 + l15] : 0.f;
    }
    const bool owave = (n2 == 0 && nh == 0);

    #pragma unroll 1
    for (int j = 0; j < NF; ++j) {
        const u64* hsrc = hPb[cur];
        f32x4 ar[2] = {zz, zz}, az2[2] = {zz, zz}, anh[2] = {zz, zz};
        f32x4 ao[2] = {zz, zz};
        {
            auto bodyD = [&](int kt, bf16x8 ah, bf16x8 al) {
                #pragma unroll
                for (int nt = 0; nt < 2; ++nt) {
                    int nn = n2 * 4 + nh * 2 + nt;
                    ar[nt]  = mfma3(ah, al, dwhh_p + ((size_t)((0 * 32 + nn) * 16 + kt) * 64 + lane) * 16, ar[nt]);
                    az2[nt] = mfma3(ah, al, dwhh_p + ((size_t)((1 * 32 + nn) * 16 + kt) * 64 + lane) * 16, az2[nt]);
                    anh[nt] = mfma3(ah, al, dwhh_p + ((size_t)((2 * 32 + nn) * 16 + kt) * 64 + lane) * 16, anh[nt]);
                }
                if (owave && j >= 1) {
                    #pragma unroll
                    for (int nt = 0; nt < 2; ++nt)
                        ao[nt] = mfma3(ah, al, outw_p + ((size_t)(nt * 16 + kt) * 64 + lane) * 16, ao[nt]);
                }
            };
            if (sdeFast) {
                const char* base = (const char*)(hsrc + (size_t)((g2 * 4 + mt) * 16) * 256) + lane * 16;
                #pragma unroll
                for (int kb = 0; kb < 4; ++kb) {
                    bf16x8 a0, c0, a1, c1, a2, c2, a3, c3;
                    ld4_fast(base + kb * 8192, base + kb * 8192 + 4096,
                             a0, c0, a1, c1, a2, c2, a3, c3);
                    bodyD(kb * 4 + 0, a0, c0);
                    bodyD(kb * 4 + 1, a1, c1);
                    bodyD(kb * 4 + 2, a2, c2);
                    bodyD(kb * 4 + 3, a3, c3);
                }
            } else {
                #pragma unroll 4
                for (int kt = 0; kt < 16; ++kt) {
                    bf16x8 ah, al;
                    ld_frag_agent(hsrc + (size_t)((g2 * 4 + mt) * 16 + kt) * 256, lane, ah, al);
                    bodyD(kt, ah, al);
                }
            }
        }
        if (owave && j >= 1) {
            #pragma unroll
            for (int nt = 0; nt < 2; ++nt)
                #pragma unroll
                for (int v = 0; v < 4; ++v) {
                    int b = b0 + g4 * 4 + v;
                    out[(((size_t)smp * NB + b) * NI + nt * 16 + l15) * NF + (j - 1)] = ao[nt][v] + obias[nt];
                }
        }
        #pragma unroll
        for (int nt = 0; nt < 2; ++nt)
            #pragma unroll
            for (int v = 0; v < 4; ++v) {
                float r = sigm(ar[nt][v] + crv[nt]);
                float z = sigm(az2[nt][v] + czv[nt]);
                float nn2 = tanhf(binv[nt] + r * (anh[nt][v] + bhnv[nt]));
                hreg[nt][v] = (1.f - z) * nn2 + z * hreg[nt][v];
                unsigned short hi, lo;
                split_bf(hreg[nt][v], hi, lo);
                Thi[mt * 16 + g4 * 4 + v][nh * 32 + nt * 16 + l15] = hi;
                Tlo[mt * 16 + g4 * 4 + v][nh * 32 + nt * 16 + l15] = lo;
            }
        __syncthreads();
        {
            bf16x8 vh = *(const bf16x8*)&Thi[tmt * 16 + (ln & 15)][ko * 32 + (ln >> 4) * 8];
            bf16x8 vl = *(const bf16x8*)&Tlo[tmt * 16 + (ln & 15)][ko * 32 + (ln >> 4) * 8];
            st_frag(hPb[cur ^ 1] + (size_t)((g2 * 4 + tmt) * 16 + n2 * 2 + ko) * 256, ln, vh, vl, sdeFast);
        }
        cur ^= 1;
        gbar(ctr2, 8u * (2 * NSTEP + j + 1));
    }
    // epilogue: final output column (j = NF)
    if (owave) {
        f32x4 ao[2] = {zz, zz};
        const u64* hsrc = hPb[cur];
        #pragma unroll 4
        for (int kt = 0; kt < 16; ++kt) {
            bf16x8 ah, al;
            if (sdeFast) {
                const char* base = (const char*)(hsrc + (size_t)((g2 * 4 + mt) * 16 + kt) * 256) + lane * 16;
                FragU a, b;
                asm volatile(
                    "global_load_dwordx4 %0, %2, off sc0\n\t"
                    "global_load_dwordx4 %1, %2, off offset:1024 sc0\n\t"
                    "s_waitcnt vmcnt(0)"
                    : "=&v"(a.u), "=&v"(b.u) : "v"(base) : "memory");
                ah = a.b; al = b.b;
            } else {
                ld_frag_agent(hsrc + (size_t)((g2 * 4 + mt) * 16 + kt) * 256, lane, ah, al);
            }
            #pragma unroll
            for (int nt = 0; nt < 2; ++nt)
                ao[nt] = mfma3(ah, al, outw_p + ((size_t)(nt * 16 + kt) * 64 + lane) * 16, ao[nt]);
        }
        #pragma unroll
        for (int nt = 0; nt < 2; ++nt)
            #pragma unroll
            for (int v = 0; v < 4; ++v) {
                int b = b0 + g4 * 4 + v;
                out[(((size_t)smp * NB + b) * NI + nt * 16 + l15) * NF + (NF - 1)] = ao[nt][v] + obias[nt];
            }
    }
}

extern "C" void kernel_launch(void* const* d_in, const int* in_sizes, int n_in,
                              void* d_out, int out_size, void* d_ws, size_t ws_size,
                              hipStream_t stream) {
    const float* x       = (const float*)d_in[0];
    const float* noise   = (const float*)d_in[1];
    const float* enc_Wih = (const float*)d_in[2];
    const float* enc_Whh = (const float*)d_in[3];
    const float* enc_bih = (const float*)d_in[4];
    const float* enc_bhh = (const float*)d_in[5];
    const float* f_W1    = (const float*)d_in[6];
    const float* f_b1    = (const float*)d_in[7];
    const float* f_W2    = (const float*)d_in[8];
    const float* f_b2    = (const float*)d_in[9];
    const float* g_W     = (const float*)d_in[10];
    const float* g_b     = (const float*)d_in[11];
    const float* dec_Whh = (const float*)d_in[13];
    const float* dec_bih = (const float*)d_in[14];
    const float* dec_bhh = (const float*)d_in[15];
    const float* out_W   = (const float*)d_in[16];
    const float* out_b   = (const float*)d_in[17];
    float* out = (float*)d_out;

    char* ws = (char*)d_ws;
    unsigned short* whh_p  = (unsigned short*)(ws + 0);          // 3 MB
    unsigned short* wih_p  = (unsigned short*)(ws + 3145728);    // 192 KB
    unsigned short* w1_p   = (unsigned short*)(ws + 3342336);    // 1 MB
    unsigned short* w2_p   = (unsigned short*)(ws + 4390912);    // 1 MB
    unsigned short* gw_p   = (unsigned short*)(ws + 5439488);    // 1 MB
    unsigned short* dwhh_p = (unsigned short*)(ws + 6488064);    // 3 MB
    unsigned short* outw_p = (unsigned short*)(ws + 9633792);    // 64 KB
    unsigned short* xhi    = (unsigned short*)(ws + 9699328);    // 768 KB
    unsigned short* xlo    = (unsigned short*)(ws + 10485760);   // 768 KB
    u64*            hE1    = (u64*)(ws + 11272192);              // 256 KB
    u64*            hP0    = (u64*)(ws + 11534336);              // 4 MB
    u64*            hP1    = (u64*)(ws + 15728640);              // 4 MB
    u64*            uP     = (u64*)(ws + 19922944);              // 4 MB
    unsigned*       h_encF = (unsigned*)(ws + 24117248);         // 256 KB
    unsigned*       bar    = (unsigned*)(ws + 24379392);         // 8 KB
    u64*            hE0    = (u64*)(ws + 24387584);              // 256 KB
    u64*            hEF    = (u64*)(ws + 24649728);              // 256 KB (agent-only)
    unsigned*       xcdArr = (unsigned*)(ws + 24911872);         // 1 KB

    // zero barrier counters only
    hipMemsetAsync(ws + 24379392, 0, 8192, stream);

    pack_w<<<384, 256, 0, stream>>>(enc_Whh, whh_p, 3 * HD, HD);
    pack_w<<<24, 256, 0, stream>>>(enc_Wih, wih_p, 3 * HD, NI);
    pack_w<<<128, 256, 0, stream>>>(f_W1, w1_p, HD, HD);
    pack_w<<<128, 256, 0, stream>>>(f_W2, w2_p, HD, HD);
    pack_w<<<128, 256, 0, stream>>>(g_W, gw_p, HD, HD);
    pack_w<<<384, 256, 0, stream>>>(dec_Whh, dwhh_p, 3 * HD, HD);
    pack_w<<<8, 256, 0, stream>>>(out_W, outw_p, NI, HD);
    pack_x<<<48, 256, 0, stream>>>(x, xhi, xlo);

    void* args[] = {
        (void*)&xhi, (void*)&xlo, (void*)&wih_p, (void*)&whh_p,
        (void*)&w1_p, (void*)&w2_p, (void*)&gw_p, (void*)&dwhh_p, (void*)&outw_p,
        (void*)&enc_bih, (void*)&enc_bhh, (void*)&f_b1, (void*)&f_b2,
        (void*)&g_b, (void*)&dec_bih, (void*)&dec_bhh, (void*)&out_b,
        (void*)&noise,
        (void*)&hE0, (void*)&hE1, (void*)&hEF, (void*)&hP0, (void*)&hP1, (void*)&uP,
        (void*)&h_encF, (void*)&xcdArr, (void*)&out, (void*)&bar
    };
    hipLaunchCooperativeKernel((void*)coop_all, dim3(256), dim3(512), args, 0, stream);
}

// Round 11
// 2267.597 us; speedup vs baseline: 1.1861x; 1.1861x over previous
//
#include <hip/hip_runtime.h>
#include <math.h>

typedef __bf16 bf16x8 __attribute__((ext_vector_type(8)));
typedef float f32x4 __attribute__((ext_vector_type(4)));
typedef unsigned long long u64;

#define HD 512
#define NB 128
#define NI 32
#define NL 96
#define NS 16
#define NF 24
#define NSTEP 23
#define TS2 72

#define MFMA16(a,b,c) __builtin_amdgcn_mfma_f32_16x16x32_bf16(a,b,c,0,0,0)

__device__ __forceinline__ unsigned short f2bf(float f) {
    union { float f; unsigned u; } v; v.f = f;
    unsigned r = v.u + 0x7fffu + ((v.u >> 16) & 1u);
    return (unsigned short)(r >> 16);
}
__device__ __forceinline__ float bf2f(unsigned short h) {
    union { unsigned u; float f; } v; v.u = ((unsigned)h) << 16;
    return v.f;
}
__device__ __forceinline__ void split_bf(float v, unsigned short& hi, unsigned short& lo) {
    unsigned short h = f2bf(v);
    hi = h;
    lo = f2bf(v - bf2f(h));
}
__device__ __forceinline__ float sigm(float x) { return 1.0f / (1.0f + __expf(-x)); }
__device__ __forceinline__ float softp(float x) {
    return fmaxf(x, 0.0f) + log1pf(__expf(-fabsf(x)));
}
__device__ __forceinline__ bf16x8 ld8(const unsigned short* p) {
    return *reinterpret_cast<const bf16x8*>(p);
}
__device__ __forceinline__ f32x4 mfma3(bf16x8 ahi, bf16x8 alo, const unsigned short* bp, f32x4 c) {
    bf16x8 bhi = ld8(bp);
    bf16x8 blo = ld8(bp + 8);
    c = MFMA16(ahi, bhi, c);
    c = MFMA16(alo, bhi, c);
    c = MFMA16(ahi, blo, c);
    return c;
}

// ---- device-coherent state exchange: relaxed agent-scope 8B atomics (proven path) ----
// tile = 64-lane fragment: hi-plane [lane*16 B] (1 KB) + lo-plane (+1 KB)
__device__ __forceinline__ void st_frag_agent(u64* tile, int lane, bf16x8 hi, bf16x8 lo) {
    union { bf16x8 v; u64 q[2]; } h, l;
    h.v = hi; l.v = lo;
    u64* t = tile + lane * 2;
    __hip_atomic_store(t + 0,   h.q[0], __ATOMIC_RELAXED, __HIP_MEMORY_SCOPE_AGENT);
    __hip_atomic_store(t + 1,   h.q[1], __ATOMIC_RELAXED, __HIP_MEMORY_SCOPE_AGENT);
    __hip_atomic_store(t + 128, l.q[0], __ATOMIC_RELAXED, __HIP_MEMORY_SCOPE_AGENT);
    __hip_atomic_store(t + 129, l.q[1], __ATOMIC_RELAXED, __HIP_MEMORY_SCOPE_AGENT);
}
__device__ __forceinline__ void ld_frag_agent(const u64* tile, int lane, bf16x8& hi, bf16x8& lo) {
    union { bf16x8 v; u64 q[2]; } h, l;
    const u64* t = tile + lane * 2;
    h.q[0] = __hip_atomic_load(t + 0,   __ATOMIC_RELAXED, __HIP_MEMORY_SCOPE_AGENT);
    h.q[1] = __hip_atomic_load(t + 1,   __ATOMIC_RELAXED, __HIP_MEMORY_SCOPE_AGENT);
    l.q[0] = __hip_atomic_load(t + 128, __ATOMIC_RELAXED, __HIP_MEMORY_SCOPE_AGENT);
    l.q[1] = __hip_atomic_load(t + 129, __ATOMIC_RELAXED, __HIP_MEMORY_SCOPE_AGENT);
    hi = h.v; lo = l.v;
}

// split barrier: signal (non-blocking) / wait. No __threadfence (no L2 dump).
__device__ __forceinline__ void bsig(unsigned* ctr) {
    __builtin_amdgcn_s_waitcnt(0);   // per-wave: own stores drained
    __syncthreads();                 // all waves drained
    if (threadIdx.x == 0)
        __hip_atomic_fetch_add(ctr, 1u, __ATOMIC_RELAXED, __HIP_MEMORY_SCOPE_AGENT);
}
__device__ __forceinline__ void bwait(unsigned* ctr, unsigned target) {
    if (threadIdx.x == 0)
        while (__hip_atomic_load(ctr, __ATOMIC_RELAXED, __HIP_MEMORY_SCOPE_AGENT) < target)
            __builtin_amdgcn_s_sleep(2);
    __syncthreads();
}
__device__ __forceinline__ void gbar(unsigned* ctr, unsigned target) {
    bsig(ctr);
    bwait(ctr, target);
}

// ---------- prep kernels ----------
__global__ void pack_w(const float* __restrict__ W, unsigned short* __restrict__ Wp,
                       int N, int K) {
    int idx = blockIdx.x * 256 + threadIdx.x;
    int total = (N / 16) * (K / 32) * 64;
    if (idx >= total) return;
    int lane = idx & 63;
    int t2 = idx >> 6;
    int KT = K / 32;
    int kt = t2 % KT, nt = t2 / KT;
    const float* src = W + (size_t)(nt * 16 + (lane & 15)) * K + kt * 32 + (lane >> 4) * 8;
    unsigned short* dst = Wp + (size_t)idx * 16;
    #pragma unroll
    for (int j = 0; j < 8; ++j) split_bf(src[j], dst[j], dst[8 + j]);
}
__global__ void pack_x(const float* __restrict__ x, unsigned short* __restrict__ xhi,
                       unsigned short* __restrict__ xlo) {
    int idx = blockIdx.x * 256 + threadIdx.x;
    if (idx >= NL * NB) return;
    int b = idx % NB, l = idx / NB;
    size_t base = (size_t)(l * NB + b) * NI;
    #pragma unroll
    for (int i = 0; i < NI; ++i)
        split_bf(x[((size_t)b * NI + i) * NL + l], xhi[base + i], xlo[base + i]);
}

// =================== fused cooperative kernel ===================
__global__ __launch_bounds__(512) void coop_all(
    const unsigned short* __restrict__ xhi, const unsigned short* __restrict__ xlo,
    const unsigned short* __restrict__ wih_p, const unsigned short* __restrict__ whh_p,
    const unsigned short* __restrict__ w1_p, const unsigned short* __restrict__ w2_p,
    const unsigned short* __restrict__ gw_p, const unsigned short* __restrict__ dwhh_p,
    const unsigned short* __restrict__ outw_p,
    const float* __restrict__ ebih, const float* __restrict__ ebhh,
    const float* __restrict__ fb1, const float* __restrict__ fb2,
    const float* __restrict__ gb, const float* __restrict__ dbih,
    const float* __restrict__ dbhh, const float* __restrict__ outb,
    const float* __restrict__ noise,
    u64* hE0, u64* hE1, u64* hEF, u64* hP0, u64* hP1, u64* uP,
    unsigned* h_encF, float* out, unsigned* bar)
{
    const int bid = blockIdx.x;
    const int tid = threadIdx.x, lane = tid & 63, wv = tid >> 6;
    const int l15 = lane & 15, g4 = lane >> 4;
    const f32x4 zz = {0.f, 0.f, 0.f, 0.f};

    __shared__ float pred[4][8][16][16];
    __shared__ __align__(16) unsigned short Thi[64][TS2];
    __shared__ __align__(16) unsigned short Tlo[64][TS2];

    // =============== encoder: 8 groups x 32 blocks (16 rows, 16-unit slices) ===============
    {
        const int g = bid & 7, n = bid >> 3;
        unsigned* ctr = bar + (2 + g) * 32;
        float hcell = 0.f;
        float cr = 0.f, cz = 0.f, binx = 0.f, bhnn = 0.f;
        const int crow = tid >> 4, cunit = tid & 15;
        if (tid < 256) {
            int u = n * 16 + cunit;
            cr = ebih[u] + ebhh[u];
            cz = ebih[HD + u] + ebhh[HD + u];
            binx = ebih[2 * HD + u];
            bhnn = ebhh[2 * HD + u];
        }
        u64* hEbuf[2] = {hE0, hE1};
        #pragma unroll 1
        for (int l = 0; l < NL; ++l) {
            const u64* cur = hEbuf[l & 1];
            u64* nxt = hEbuf[(l & 1) ^ 1];
            f32x4 pr = zz, pz = zz, pnh = zz, pnx = zz;
            if (wv == 0) {
                size_t xb = (size_t)(l * NB + g * 16 + l15) * NI + g4 * 8;
                bf16x8 axh = ld8(xhi + xb), axl = ld8(xlo + xb);
                pr  = mfma3(axh, axl, wih_p + ((size_t)(0 * 32 + n) * 64 + lane) * 16, pr);
                pz  = mfma3(axh, axl, wih_p + ((size_t)(1 * 32 + n) * 64 + lane) * 16, pz);
                pnx = mfma3(axh, axl, wih_p + ((size_t)(2 * 32 + n) * 64 + lane) * 16, pnx);
            }
            if (l > 0) {   // l==0: h == 0, skip hh matmul (avoids reading uninit hE0)
                #pragma unroll
                for (int kk = 0; kk < 2; ++kk) {
                    int kt = wv * 2 + kk;
                    bf16x8 ah, al;
                    ld_frag_agent(cur + (size_t)(g * 16 + kt) * 256, lane, ah, al);
                    pr  = mfma3(ah, al, whh_p + ((size_t)((0 * 32 + n) * 16 + kt) * 64 + lane) * 16, pr);
                    pz  = mfma3(ah, al, whh_p + ((size_t)((1 * 32 + n) * 16 + kt) * 64 + lane) * 16, pz);
                    pnh = mfma3(ah, al, whh_p + ((size_t)((2 * 32 + n) * 16 + kt) * 64 + lane) * 16, pnh);
                }
            }
            #pragma unroll
            for (int v = 0; v < 4; ++v) {
                pred[0][wv][g4 * 4 + v][l15] = pr[v];
                pred[1][wv][g4 * 4 + v][l15] = pz[v];
                pred[2][wv][g4 * 4 + v][l15] = pnh[v];
                if (wv == 0) pred[3][0][g4 * 4 + v][l15] = pnx[v];
            }
            __syncthreads();
            if (tid < 256) {
                float ar = 0.f, az = 0.f, anh_ = 0.f;
                #pragma unroll
                for (int w = 0; w < 8; ++w) {
                    ar += pred[0][w][crow][cunit];
                    az += pred[1][w][crow][cunit];
                    anh_ += pred[2][w][crow][cunit];
                }
                float anx_ = pred[3][0][crow][cunit];
                float r = sigm(ar + cr);
                float z = sigm(az + cz);
                float nn = tanhf(anx_ + binx + r * (anh_ + bhnn));
                hcell = (1.f - z) * nn + z * hcell;
                unsigned short hi, lo;
                split_bf(hcell, hi, lo);
                Thi[crow][cunit] = hi;
                Tlo[crow][cunit] = lo;
                if (l == NL - 1)
                    __hip_atomic_store(h_encF + (size_t)(g * 16 + crow) * HD + n * 16 + cunit,
                                       __float_as_uint(hcell),
                                       __ATOMIC_RELAXED, __HIP_MEMORY_SCOPE_AGENT);
            }
            __syncthreads();
            if (tid < 32) {
                int half = n & 1, kt = n >> 1;
                int lp = half * 32 + tid;
                bf16x8 vh = *(const bf16x8*)&Thi[tid & 15][(tid >> 4) * 8];
                bf16x8 vl = *(const bf16x8*)&Tlo[tid & 15][(tid >> 4) * 8];
                if (l == NL - 1)
                    st_frag_agent(hEF + (size_t)(g * 16 + kt) * 256, lp, vh, vl);
                else
                    st_frag_agent(nxt + (size_t)(g * 16 + kt) * 256, lp, vh, vl);
            }
            gbar(ctr, 32u * (l + 1));
        }
    }

    // full-grid barrier: h_encF + hEF visible to all
    gbar(bar, 256u);

    // ====== SDE + decoder: 64 groups x 8 blocks; group = 32 rows, slice = 64 units.
    //        Each block dual-homes TWO groups (gA, gB) and software-pipelines their
    //        phases so every barrier wait is preceded by the sibling's compute. ======
    const int gA = (bid & 31) * 2, gB = gA + 1;
    const int n2 = bid >> 5;                       // 0..7: 64-unit slice
    unsigned* ctrA = bar + (16 + gA) * 32;
    unsigned* ctrB = bar + (16 + gB) * 32;
    const int mt = wv & 1, nsub = wv >> 1;         // wave = (m-tile of 16 rows, 16-unit subslice)
    const int uc = n2 * 64 + nsub * 16;            // this wave's unit column base
    const int wrow = mt * 16 + g4 * 4;             // row base within group (plus v)
    const float dt = (float)NF / (float)NSTEP;
    const float sqdt = sqrtf(dt);

    const float b1v = fb1[uc + l15], b2v = fb2[uc + l15], gbv = gb[uc + l15];

    float hreg[2][4];
    #pragma unroll
    for (int gi = 0; gi < 2; ++gi) {
        int g = gA + gi;
        #pragma unroll
        for (int v = 0; v < 4; ++v)
            hreg[gi][v] = __uint_as_float(__hip_atomic_load(
                h_encF + (size_t)((g & 3) * 32 + wrow + v) * HD + uc + l15,
                __ATOMIC_RELAXED, __HIP_MEMORY_SCOPE_AGENT));
    }

    u64* hPb[2] = {hP0, hP1};
    int cur = 0;

    // ---------------- SDE Euler-Maruyama (dual-group pipelined) ----------------
    f32x4 agv[2];        // softplus-pre, computed in phase A, consumed in B
    float nzv[2][4];     // noise prefetch

    #pragma unroll 1
    for (int st = 0; st < NSTEP; ++st) {
        #pragma unroll
        for (int gi = 0; gi < 2; ++gi) {          // ---- phase A for gA then gB ----
            int g = gA + gi;
            unsigned* ctr = gi ? ctrB : ctrA;
            if (st > 0) bwait(ctr, 16u * st);
            // noise prefetch for phase B
            #pragma unroll
            for (int v = 0; v < 4; ++v) {
                int b = (g & 3) * 32 + wrow + v;
                nzv[gi][v] = noise[((size_t)((g >> 2) * NSTEP + st) * NB + b) * HD + uc + l15];
            }
            f32x4 au = zz, ag = zz;
            if (st == 0) {
                int mt0 = (g & 3) * 2 + mt;
                #pragma unroll 4
                for (int kt = 0; kt < 16; ++kt) {
                    bf16x8 ah, al;
                    ld_frag_agent(hEF + (size_t)(mt0 * 16 + kt) * 256, lane, ah, al);
                    au = mfma3(ah, al, w1_p + ((size_t)((n2 * 4 + nsub) * 16 + kt) * 64 + lane) * 16, au);
                    ag = mfma3(ah, al, gw_p + ((size_t)((n2 * 4 + nsub) * 16 + kt) * 64 + lane) * 16, ag);
                }
            } else {
                const u64* hsrc = hPb[cur];
                #pragma unroll 4
                for (int kt = 0; kt < 16; ++kt) {
                    bf16x8 ah, al;
                    ld_frag_agent(hsrc + (size_t)((g * 2 + mt) * 16 + kt) * 256, lane, ah, al);
                    au = mfma3(ah, al, w1_p + ((size_t)((n2 * 4 + nsub) * 16 + kt) * 64 + lane) * 16, au);
                    ag = mfma3(ah, al, gw_p + ((size_t)((n2 * 4 + nsub) * 16 + kt) * 64 + lane) * 16, ag);
                }
            }
            agv[gi] = ag;
            #pragma unroll
            for (int v = 0; v < 4; ++v) {
                unsigned short hi, lo;
                split_bf(tanhf(au[v] + b1v), hi, lo);
                Thi[wrow + v][nsub * 16 + l15] = hi;
                Tlo[wrow + v][nsub * 16 + l15] = lo;
            }
            __syncthreads();
            if (wv < 4) {
                int tmt = wv & 1, ko = wv >> 1;
                bf16x8 vh = *(const bf16x8*)&Thi[tmt * 16 + (lane & 15)][ko * 32 + (lane >> 4) * 8];
                bf16x8 vl = *(const bf16x8*)&Tlo[tmt * 16 + (lane & 15)][ko * 32 + (lane >> 4) * 8];
                st_frag_agent(uP + (size_t)((g * 2 + tmt) * 16 + n2 * 2 + ko) * 256, lane, vh, vl);
            }
            bsig(ctr);
        }
        #pragma unroll
        for (int gi = 0; gi < 2; ++gi) {          // ---- phase B for gA then gB ----
            int g = gA + gi;
            unsigned* ctr = gi ? ctrB : ctrA;
            bwait(ctr, 16u * st + 8u);
            f32x4 af = zz;
            #pragma unroll 4
            for (int kt = 0; kt < 16; ++kt) {
                bf16x8 uh, ul;
                ld_frag_agent(uP + (size_t)((g * 2 + mt) * 16 + kt) * 256, lane, uh, ul);
                af = mfma3(uh, ul, w2_p + ((size_t)((n2 * 4 + nsub) * 16 + kt) * 64 + lane) * 16, af);
            }
            #pragma unroll
            for (int v = 0; v < 4; ++v) {
                float f = af[v] + b2v;
                float gg = softp(agv[gi][v] + gbv);
                hreg[gi][v] += f * dt + gg * sqdt * nzv[gi][v];
                unsigned short hi, lo;
                split_bf(hreg[gi][v], hi, lo);
                Thi[wrow + v][nsub * 16 + l15] = hi;
                Tlo[wrow + v][nsub * 16 + l15] = lo;
            }
            __syncthreads();
            if (wv < 4) {
                int tmt = wv & 1, ko = wv >> 1;
                bf16x8 vh = *(const bf16x8*)&Thi[tmt * 16 + (lane & 15)][ko * 32 + (lane >> 4) * 8];
                bf16x8 vl = *(const bf16x8*)&Tlo[tmt * 16 + (lane & 15)][ko * 32 + (lane >> 4) * 8];
                st_frag_agent(hPb[cur ^ 1] + (size_t)((g * 2 + tmt) * 16 + n2 * 2 + ko) * 256, lane, vh, vl);
            }
            bsig(ctr);
        }
        cur ^= 1;
    }

    // ---------------- decoder GRU + out-proj (dual-group pipelined) ----------------
    const float crv  = dbih[uc + l15] + dbhh[uc + l15];
    const float czv  = dbih[HD + uc + l15] + dbhh[HD + uc + l15];
    const float binv = dbih[2 * HD + uc + l15];
    const float bhnv = dbhh[2 * HD + uc + l15];
    const bool oblock = (n2 == 0);
    const int ft = wv >> 1;                       // feature tile for out-proj (valid if <2)
    const bool owave = oblock && (ft < 2);
    const float obias = owave ? outb[ft * 16 + l15] : 0.f;

    #pragma unroll 1
    for (int j = 0; j < NF; ++j) {
        #pragma unroll
        for (int gi = 0; gi < 2; ++gi) {
            int g = gA + gi;
            unsigned* ctr = gi ? ctrB : ctrA;
            bwait(ctr, 16u * NSTEP + 8u * j);
            const u64* hsrc = hPb[cur];
            f32x4 ar = zz, az2 = zz, anh = zz, ao = zz;
            #pragma unroll 4
            for (int kt = 0; kt < 16; ++kt) {
                bf16x8 ah, al;
                ld_frag_agent(hsrc + (size_t)((g * 2 + mt) * 16 + kt) * 256, lane, ah, al);
                int nn = n2 * 4 + nsub;
                ar  = mfma3(ah, al, dwhh_p + ((size_t)((0 * 32 + nn) * 16 + kt) * 64 + lane) * 16, ar);
                az2 = mfma3(ah, al, dwhh_p + ((size_t)((1 * 32 + nn) * 16 + kt) * 64 + lane) * 16, az2);
                anh = mfma3(ah, al, dwhh_p + ((size_t)((2 * 32 + nn) * 16 + kt) * 64 + lane) * 16, anh);
                if (owave && j >= 1)
                    ao = mfma3(ah, al, outw_p + ((size_t)(ft * 16 + kt) * 64 + lane) * 16, ao);
            }
            if (owave && j >= 1) {
                #pragma unroll
                for (int v = 0; v < 4; ++v) {
                    int b = (g & 3) * 32 + wrow + v;
                    out[(((size_t)(g >> 2) * NB + b) * NI + ft * 16 + l15) * NF + (j - 1)] = ao[v] + obias;
                }
            }
            #pragma unroll
            for (int v = 0; v < 4; ++v) {
                float r = sigm(ar[v] + crv);
                float z = sigm(az2[v] + czv);
                float nn2 = tanhf(binv + r * (anh[v] + bhnv));
                hreg[gi][v] = (1.f - z) * nn2 + z * hreg[gi][v];
                unsigned short hi, lo;
                split_bf(hreg[gi][v], hi, lo);
                Thi[wrow + v][nsub * 16 + l15] = hi;
                Tlo[wrow + v][nsub * 16 + l15] = lo;
            }
            __syncthreads();
            if (wv < 4) {
                int tmt = wv & 1, ko = wv >> 1;
                bf16x8 vh = *(const bf16x8*)&Thi[tmt * 16 + (lane & 15)][ko * 32 + (lane >> 4) * 8];
                bf16x8 vl = *(const bf16x8*)&Tlo[tmt * 16 + (lane & 15)][ko * 32 + (lane >> 4) * 8];
                st_frag_agent(hPb[cur ^ 1] + (size_t)((g * 2 + tmt) * 16 + n2 * 2 + ko) * 256, lane, vh, vl);
            }
            bsig(ctr);
        }
        cur ^= 1;
    }
    // epilogue: final output column from post-loop h (block-uniform branch)
    if (oblock) {
        #pragma unroll
        for (int gi = 0; gi < 2; ++gi) {
            int g = gA + gi;
            unsigned* ctr = gi ? ctrB : ctrA;
            bwait(ctr, 16u * NSTEP + 8u * NF);
            if (ft < 2) {
                f32x4 ao = zz;
                const u64* hsrc = hPb[cur];
                #pragma unroll 4
                for (int kt = 0; kt < 16; ++kt) {
                    bf16x8 ah, al;
                    ld_frag_agent(hsrc + (size_t)((g * 2 + mt) * 16 + kt) * 256, lane, ah, al);
                    ao = mfma3(ah, al, outw_p + ((size_t)(ft * 16 + kt) * 64 + lane) * 16, ao);
                }
                #pragma unroll
                for (int v = 0; v < 4; ++v) {
                    int b = (g & 3) * 32 + wrow + v;
                    out[(((size_t)(g >> 2) * NB + b) * NI + ft * 16 + l15) * NF + (NF - 1)] = ao[v] + obias;
                }
            }
        }
    }
}

extern "C" void kernel_launch(void* const* d_in, const int* in_sizes, int n_in,
                              void* d_out, int out_size, void* d_ws, size_t ws_size,
                              hipStream_t stream) {
    const float* x       = (const float*)d_in[0];
    const float* noise   = (const float*)d_in[1];
    const float* enc_Wih = (const float*)d_in[2];
    const float* enc_Whh = (const float*)d_in[3];
    const float* enc_bih = (const float*)d_in[4];
    const float* enc_bhh = (const float*)d_in[5];
    const float* f_W1    = (const float*)d_in[6];
    const float* f_b1    = (const float*)d_in[7];
    const float* f_W2    = (const float*)d_in[8];
    const float* f_b2    = (const float*)d_in[9];
    const float* g_W     = (const float*)d_in[10];
    const float* g_b     = (const float*)d_in[11];
    const float* dec_Whh = (const float*)d_in[13];
    const float* dec_bih = (const float*)d_in[14];
    const float* dec_bhh = (const float*)d_in[15];
    const float* out_W   = (const float*)d_in[16];
    const float* out_b   = (const float*)d_in[17];
    float* out = (float*)d_out;

    char* ws = (char*)d_ws;
    unsigned short* whh_p  = (unsigned short*)(ws + 0);          // 3 MB
    unsigned short* wih_p  = (unsigned short*)(ws + 3145728);    // 192 KB
    unsigned short* w1_p   = (unsigned short*)(ws + 3342336);    // 1 MB
    unsigned short* w2_p   = (unsigned short*)(ws + 4390912);    // 1 MB
    unsigned short* gw_p   = (unsigned short*)(ws + 5439488);    // 1 MB
    unsigned short* dwhh_p = (unsigned short*)(ws + 6488064);    // 3 MB
    unsigned short* outw_p = (unsigned short*)(ws + 9633792);    // 64 KB
    unsigned short* xhi    = (unsigned short*)(ws + 9699328);    // 768 KB
    unsigned short* xlo    = (unsigned short*)(ws + 10485760);   // 768 KB
    u64*            hE1    = (u64*)(ws + 11272192);              // 256 KB
    u64*            hP0    = (u64*)(ws + 11534336);              // 4 MB
    u64*            hP1    = (u64*)(ws + 15728640);              // 4 MB
    u64*            uP     = (u64*)(ws + 19922944);              // 4 MB
    unsigned*       h_encF = (unsigned*)(ws + 24117248);         // 256 KB
    unsigned*       bar    = (unsigned*)(ws + 24379392);         // 16 KB (grid + 8 enc + 64 sde ctrs)
    u64*            hE0    = (u64*)(ws + 24395776);              // 256 KB
    u64*            hEF    = (u64*)(ws + 24657920);              // 256 KB (agent-only)

    // zero barrier counters only
    hipMemsetAsync(ws + 24379392, 0, 16384, stream);

    pack_w<<<384, 256, 0, stream>>>(enc_Whh, whh_p, 3 * HD, HD);
    pack_w<<<24, 256, 0, stream>>>(enc_Wih, wih_p, 3 * HD, NI);
    pack_w<<<128, 256, 0, stream>>>(f_W1, w1_p, HD, HD);
    pack_w<<<128, 256, 0, stream>>>(f_W2, w2_p, HD, HD);
    pack_w<<<128, 256, 0, stream>>>(g_W, gw_p, HD, HD);
    pack_w<<<384, 256, 0, stream>>>(dec_Whh, dwhh_p, 3 * HD, HD);
    pack_w<<<8, 256, 0, stream>>>(out_W, outw_p, NI, HD);
    pack_x<<<48, 256, 0, stream>>>(x, xhi, xlo);

    void* args[] = {
        (void*)&xhi, (void*)&xlo, (void*)&wih_p, (void*)&whh_p,
        (void*)&w1_p, (void*)&w2_p, (void*)&gw_p, (void*)&dwhh_p, (void*)&outw_p,
        (void*)&enc_bih, (void*)&enc_bhh, (void*)&f_b1, (void*)&f_b2,
        (void*)&g_b, (void*)&dec_bih, (void*)&dec_bhh, (void*)&out_b,
        (void*)&noise,
        (void*)&hE0, (void*)&hE1, (void*)&hEF, (void*)&hP0, (void*)&hP1, (void*)&uP,
        (void*)&h_encF, (void*)&out, (void*)&bar
    };
    hipLaunchCooperativeKernel((void*)coop_all, dim3(256), dim3(512), args, 0, stream);
}